// Round 5
// baseline (216.156 us; speedup 1.0000x reference)
//
#include <hip/hip_runtime.h>

#define N_NODES   100000
#define N_EDGES   1600000
#define N_GRAPHS  128
#define HIDDEN    128
#define N_CLASSES 10

#define BSH   6                   // bucket = 64 nodes
#define BSZ   64
#define NBUCK 1563                // ceil(100000/64)
#define NPAD  (NBUCK * BSZ)       // 100032
#define NBIN  2048                // histogram bins (>= NBUCK), 4 per thread
#define CAP   2048                // mean fill 1024, 2x headroom
#define PCH   4096                // edges per partition block
#define PTH   512                 // partition threads
#define PIT   (PCH / PTH)         // 8 edges cached per thread

typedef unsigned int   uint;
typedef unsigned short ushort;
typedef unsigned char  uchar;

// ---- 512-wide exclusive scan: wave shfl scan + tiny cross-wave fixup (2 syncs)
__device__ __forceinline__ uint scan_excl_512(uint v, int t, uint* wtmp) {
    uint lane = (uint)(t & 63);
    uint incl = v;
    #pragma unroll
    for (int off = 1; off < 64; off <<= 1) {
        uint up = __shfl_up(incl, off, 64);
        if (lane >= (uint)off) incl += up;
    }
    if (lane == 63) wtmp[t >> 6] = incl;
    __syncthreads();
    uint wo = 0;
    int w = t >> 6;
    #pragma unroll
    for (int k = 0; k < 7; ++k) wo += (k < w) ? wtmp[k] : 0u;
    __syncthreads();                 // wtmp reusable by next call
    return incl + wo - v;
}

// -------- partition into 64-node buckets; two phases share staging buffer;
//          src/dst register-cached (one global read of each edge array).
__global__ __launch_bounds__(PTH)
void k_part(const int* __restrict__ src, const int* __restrict__ dst,
            uint* __restrict__ bcur1, uint* __restrict__ bcur2,
            uint* __restrict__ tmp1, uchar* __restrict__ tmp2, int nE) {
    __shared__ uint   hist[NBIN], lcur[NBIN], base[NBIN];   // 24 KB
    __shared__ uint   wtmp[8];
    __shared__ uint   stag4[PCH];        // 16 KB
    __shared__ ushort stagB[PCH];        // 8 KB (phase 1 only)
    int t = threadIdx.x;
    int e0 = blockIdx.x * PCH;
    int e1 = min(e0 + PCH, nE);
    int cntE = e1 - e0;

    int sv[PIT], dv[PIT];
    // ---------------- phase 1: dst ----------------
    hist[t] = 0; hist[t + 512] = 0; hist[t + 1024] = 0; hist[t + 1536] = 0;
    __syncthreads();
    #pragma unroll
    for (int m = 0; m < PIT; ++m) {
        int e = e0 + t + m * PTH;
        if (e < e1) {
            sv[m] = src[e]; dv[m] = dst[e];
            atomicAdd(&hist[dv[m] >> BSH], 1u);
        }
    }
    __syncthreads();
    {
        uint v0 = hist[4*t], v1 = hist[4*t+1], v2 = hist[4*t+2], v3 = hist[4*t+3];
        uint ssum = v0 + v1 + v2 + v3;
        uint ex = scan_excl_512(ssum, t, wtmp);
        uint l0 = ex, l1 = ex + v0, l2 = l1 + v1, l3 = l2 + v2;
        lcur[4*t] = l0; lcur[4*t+1] = l1; lcur[4*t+2] = l2; lcur[4*t+3] = l3;
        if (v0) { uint g = atomicAdd(&bcur1[4*t+0], v0); base[4*t+0] = (uint)(4*t+0) * CAP + g - l0; }
        if (v1) { uint g = atomicAdd(&bcur1[4*t+1], v1); base[4*t+1] = (uint)(4*t+1) * CAP + g - l1; }
        if (v2) { uint g = atomicAdd(&bcur1[4*t+2], v2); base[4*t+2] = (uint)(4*t+2) * CAP + g - l2; }
        if (v3) { uint g = atomicAdd(&bcur1[4*t+3], v3); base[4*t+3] = (uint)(4*t+3) * CAP + g - l3; }
    }
    __syncthreads();
    #pragma unroll
    for (int m = 0; m < PIT; ++m) {
        int e = e0 + t + m * PTH;
        if (e < e1) {
            int d = dv[m], s = sv[m];
            int b = d >> BSH;
            uint p = atomicAdd(&lcur[b], 1u);
            stag4[p] = ((uint)(d & (BSZ - 1)) << 17) | (uint)s;
            stagB[p] = (ushort)b;
        }
    }
    __syncthreads();
    for (int i = t; i < cntE; i += PTH) {
        uint b = stagB[i];
        uint a = base[b] + (uint)i;
        if (a < (b + 1u) * CAP) tmp1[a] = stag4[i];
    }
    __syncthreads();

    // ---------------- phase 2: src ----------------
    hist[t] = 0; hist[t + 512] = 0; hist[t + 1024] = 0; hist[t + 1536] = 0;
    __syncthreads();
    #pragma unroll
    for (int m = 0; m < PIT; ++m) {
        int e = e0 + t + m * PTH;
        if (e < e1) atomicAdd(&hist[sv[m] >> BSH], 1u);
    }
    __syncthreads();
    {
        uint v0 = hist[4*t], v1 = hist[4*t+1], v2 = hist[4*t+2], v3 = hist[4*t+3];
        uint ssum = v0 + v1 + v2 + v3;
        uint ex = scan_excl_512(ssum, t, wtmp);
        uint l0 = ex, l1 = ex + v0, l2 = l1 + v1, l3 = l2 + v2;
        lcur[4*t] = l0; lcur[4*t+1] = l1; lcur[4*t+2] = l2; lcur[4*t+3] = l3;
        if (v0) { uint g = atomicAdd(&bcur2[4*t+0], v0); base[4*t+0] = (uint)(4*t+0) * CAP + g - l0; }
        if (v1) { uint g = atomicAdd(&bcur2[4*t+1], v1); base[4*t+1] = (uint)(4*t+1) * CAP + g - l1; }
        if (v2) { uint g = atomicAdd(&bcur2[4*t+2], v2); base[4*t+2] = (uint)(4*t+2) * CAP + g - l2; }
        if (v3) { uint g = atomicAdd(&bcur2[4*t+3], v3); base[4*t+3] = (uint)(4*t+3) * CAP + g - l3; }
    }
    __syncthreads();
    #pragma unroll
    for (int m = 0; m < PIT; ++m) {
        int e = e0 + t + m * PTH;
        if (e < e1) {
            int s = sv[m];
            uint p = atomicAdd(&lcur[s >> BSH], 1u);
            stag4[p] = (uint)s;
        }
    }
    __syncthreads();
    for (int i = t; i < cntE; i += PTH) {
        uint s = stag4[i];
        uint b = s >> BSH;
        uint a = base[b] + (uint)i;
        if (a < (b + 1u) * CAP) tmp2[a] = (uchar)(s & (BSZ - 1));
    }
}

// ------- per bucket (bucket-complete): degrees in LDS -> ns / hs0 / ndv
__global__ __launch_bounds__(256)
void k_cnt(const uint* __restrict__ bcur1, const uint* __restrict__ tmp1,
           const uint* __restrict__ bcur2, const uchar* __restrict__ tmp2,
           float* __restrict__ ns, float* __restrict__ hs0, float* __restrict__ ndv) {
    __shared__ uint cin[BSZ], cout[BSZ];
    int b = blockIdx.x, t = threadIdx.x;
    if (t < BSZ) { cin[t] = 0; cout[t] = 0; }
    __syncthreads();
    uint f1 = min(bcur1[b], (uint)CAP);
    const uint* tp1 = tmp1 + (size_t)b * CAP;
    uint i = t;
    for (; i + 768u < f1; i += 1024u) {
        uint a0 = tp1[i], a1 = tp1[i + 256], a2 = tp1[i + 512], a3 = tp1[i + 768];
        atomicAdd(&cin[a0 >> 17], 1u); atomicAdd(&cin[a1 >> 17], 1u);
        atomicAdd(&cin[a2 >> 17], 1u); atomicAdd(&cin[a3 >> 17], 1u);
    }
    for (; i < f1; i += 256u) atomicAdd(&cin[tp1[i] >> 17], 1u);

    uint f2 = min(bcur2[b], (uint)CAP);
    const uchar* tp2 = tmp2 + (size_t)b * CAP;
    const uint* tp2w = (const uint*)tp2;         // CAP-aligned (2048B)
    uint nw = f2 >> 2;
    for (i = t; i < nw; i += 256u) {
        uint w4 = tp2w[i];
        atomicAdd(&cout[w4 & 63u], 1u);
        atomicAdd(&cout[(w4 >> 8) & 63u], 1u);
        atomicAdd(&cout[(w4 >> 16) & 63u], 1u);
        atomicAdd(&cout[(w4 >> 24) & 63u], 1u);
    }
    for (i = (nw << 2) + t; i < f2; i += 256u) atomicAdd(&cout[tp2[i]], 1u);
    __syncthreads();
    if (t < BSZ) {
        int n = b * BSZ + t;
        if (n < N_NODES) {
            uint ci = cin[t];
            float nsv = rsqrtf(fmaxf((float)cout[t], 1.0f));
            ns[n]  = nsv;
            hs0[n] = (float)ci * nsv;                  // h0 = indeg; hs0 = h0*norm_src
            ndv[n] = rsqrtf(fmaxf((float)ci, 1.0f));   // norm_dst
        }
    }
}

// ---- conv1 agg per bucket (LDS float atomics, bucket-complete) + node info;
//      U/V segment table computed by blocks < 129.
__global__ __launch_bounds__(256)
void k_info(const uint* __restrict__ bcur1, const uint* __restrict__ tmp1,
            const float* __restrict__ hs0, const float* __restrict__ ns,
            const float* __restrict__ ndv,
            const float* __restrict__ W1, const float* __restrict__ b1,
            const float* __restrict__ W2,
            float* __restrict__ U, float* __restrict__ V,
            float4* __restrict__ info) {
    __shared__ float agg[BSZ];
    __shared__ float stu[128];        // unsorted breakpoints
    __shared__ float sts[128];        // sorted (blocks < 129 only)
    int b = blockIdx.x, t = threadIdx.x;
    if (t < BSZ) agg[t] = 0.0f;
    if (t < 128) {
        float w = W1[t], bb = b1[t];
        stu[t] = (w != 0.0f) ? (-bb / w) : 1e30f;
    }
    __syncthreads();
    if (b < 129) {                    // block-uniform branch: syncs legal
        if (t < 128) sts[t] = stu[t];
        __syncthreads();
        for (int k = 2; k <= 128; k <<= 1) {
            for (int j = k >> 1; j > 0; j >>= 1) {
                if (t < 128) {
                    int ixj = t ^ j;
                    if (ixj > t) {
                        float a = sts[t], bb = sts[ixj];
                        bool up = ((t & k) == 0);
                        if (up ? (a > bb) : (a < bb)) { sts[t] = bb; sts[ixj] = a; }
                    }
                }
                __syncthreads();
            }
        }
        if (t < 128) {                // segment-table row, unconditional W2 loads
            int sg = b;
            float a_rep;
            if (sg == 0)        a_rep = sts[0]   - 1.0f;
            else if (sg == 128) a_rep = sts[127] + 1.0f;
            else                a_rep = 0.5f * (sts[sg - 1] + sts[sg]);
            float u = 0.0f, vv = 0.0f;
            #pragma unroll 8
            for (int j = 0; j < 128; ++j) {
                float w  = W1[j], bb = b1[j];
                float w2 = W2[j * HIDDEN + t];
                bool on  = (a_rep * w + bb > 0.0f);
                u  += on ? w  * w2 : 0.0f;
                vv += on ? bb * w2 : 0.0f;
            }
            U[sg * HIDDEN + t] = u;
            V[sg * HIDDEN + t] = vv;
        }
    }
    // edge accumulate: agg[dl] += hs0[src], 4-way MLP
    uint f1 = min(bcur1[b], (uint)CAP);
    const uint* tp1 = tmp1 + (size_t)b * CAP;
    uint i = t;
    for (; i + 768u < f1; i += 1024u) {
        uint e0 = tp1[i], e1 = tp1[i + 256], e2 = tp1[i + 512], e3 = tp1[i + 768];
        float h0 = hs0[e0 & 0x1FFFFu], h1 = hs0[e1 & 0x1FFFFu];
        float h2 = hs0[e2 & 0x1FFFFu], h3 = hs0[e3 & 0x1FFFFu];
        atomicAdd(&agg[e0 >> 17], h0); atomicAdd(&agg[e1 >> 17], h1);
        atomicAdd(&agg[e2 >> 17], h2); atomicAdd(&agg[e3 >> 17], h3);
    }
    for (; i < f1; i += 256u) {
        uint e = tp1[i];
        atomicAdd(&agg[e >> 17], hs0[e & 0x1FFFFu]);
    }
    __syncthreads();
    if (t < BSZ) {
        int n = b * BSZ + t;
        if (n < N_NODES) {
            float nd = ndv[n];
            float av = agg[t] * nd;
            int sgp = 0;
            #pragma unroll 16
            for (int q = 0; q < 128; ++q) sgp += (stu[q] < av) ? 1 : 0;
            float nsv = ns[n];
            info[n] = make_float4(nsv * av, nsv, __int_as_float(sgp), nd);
        }
    }
}

// ---- conv2 per bucket: LDS accumulate (A,B,min/max sg) over edges (4-way MLP),
//      then rows (2 node-groups x 128 dims) + flush-on-change pooling.
__global__ __launch_bounds__(256)
void k_conv2(const uint* __restrict__ bcur1, const uint* __restrict__ tmp1,
             const float4* __restrict__ info, const float* __restrict__ ndv,
             const float* __restrict__ U, const float* __restrict__ V,
             const int* __restrict__ graph_ids, const float* __restrict__ b2,
             float* __restrict__ pool, float* __restrict__ cnt) {
    __shared__ float lA[BSZ], lB[BSZ];
    __shared__ uint  lmn[BSZ], lmx[BSZ];
    int b = blockIdx.x, t = threadIdx.x;
    if (t < BSZ) { lA[t] = 0.0f; lB[t] = 0.0f; lmn[t] = 255u; lmx[t] = 0u; }
    __syncthreads();
    uint f1 = min(bcur1[b], (uint)CAP);
    const uint* tp1 = tmp1 + (size_t)b * CAP;
    uint i = t;
    for (; i + 768u < f1; i += 1024u) {
        uint e0 = tp1[i], e1 = tp1[i + 256], e2 = tp1[i + 512], e3 = tp1[i + 768];
        float4 n0 = info[e0 & 0x1FFFFu];
        float4 n1 = info[e1 & 0x1FFFFu];
        float4 n2 = info[e2 & 0x1FFFFu];
        float4 n3 = info[e3 & 0x1FFFFu];
        uint d0 = e0 >> 17, d1 = e1 >> 17, d2 = e2 >> 17, d3 = e3 >> 17;
        atomicAdd(&lA[d0], n0.x); atomicAdd(&lB[d0], n0.y);
        atomicAdd(&lA[d1], n1.x); atomicAdd(&lB[d1], n1.y);
        atomicAdd(&lA[d2], n2.x); atomicAdd(&lB[d2], n2.y);
        atomicAdd(&lA[d3], n3.x); atomicAdd(&lB[d3], n3.y);
        uint s0 = (uint)__float_as_int(n0.z), s1 = (uint)__float_as_int(n1.z);
        uint s2 = (uint)__float_as_int(n2.z), s3 = (uint)__float_as_int(n3.z);
        atomicMin(&lmn[d0], s0); atomicMax(&lmx[d0], s0);
        atomicMin(&lmn[d1], s1); atomicMax(&lmx[d1], s1);
        atomicMin(&lmn[d2], s2); atomicMax(&lmx[d2], s2);
        atomicMin(&lmn[d3], s3); atomicMax(&lmx[d3], s3);
    }
    for (; i < f1; i += 256u) {
        uint e = tp1[i];
        uint dl = e >> 17;
        float4 nf = info[e & 0x1FFFFu];
        atomicAdd(&lA[dl], nf.x);
        atomicAdd(&lB[dl], nf.y);
        uint sg = (uint)__float_as_int(nf.z);
        atomicMin(&lmn[dl], sg);
        atomicMax(&lmx[dl], sg);
    }
    __syncthreads();

    int d = t & 127, j = t >> 7;           // 2 node-groups x 128 dims
    float bbd = b2[d];
    int base = b * BSZ;
    int gcur = -1; float racc = 0.0f, cl = 0.0f;
    for (int r = j; r < BSZ; r += 2) {
        int n = base + r;
        if (n >= N_NODES) break;
        uint mn = lmn[r], mx = lmx[r];
        float acc;
        if (mn >= mx) {                    // uniform segment (or no edges: A=B=0)
            uint sg = min(mn, 128u);
            acc = lA[r] * U[sg * HIDDEN + d] + lB[r] * V[sg * HIDDEN + d];
        } else {                           // mixed: exact rescan of bucket edges (rare)
            acc = 0.0f;
            for (uint k = 0; k < f1; ++k) {
                uint e = tp1[k];
                if ((e >> 17) == (uint)r) {
                    float4 nf = info[e & 0x1FFFFu];
                    uint sg = (uint)__float_as_int(nf.z);
                    acc += nf.x * U[sg * HIDDEN + d] + nf.y * V[sg * HIDDEN + d];
                }
            }
        }
        float row = fmaxf(ndv[n] * acc + bbd, 0.0f);
        int g = graph_ids[n];
        if (g != gcur) {
            if (gcur >= 0) {
                atomicAdd(&pool[gcur * HIDDEN + d], racc);
                if (d == 0) atomicAdd(&cnt[gcur], cl);
            }
            gcur = g; racc = 0.0f; cl = 0.0f;
        }
        racc += row; cl += 1.0f;
    }
    if (gcur >= 0) {
        atomicAdd(&pool[gcur * HIDDEN + d], racc);
        if (d == 0) atomicAdd(&cnt[gcur], cl);
    }
}

// ----------------------------------------------- classifier head (tiny)
__global__ void k_final(const float* __restrict__ pool, const float* __restrict__ cnt,
                        const float* __restrict__ Wc, const float* __restrict__ bc,
                        float* __restrict__ out) {
    int t = blockIdx.x * blockDim.x + threadIdx.x;
    if (t >= N_GRAPHS * N_CLASSES) return;
    int g = t / N_CLASSES, c = t % N_CLASSES;
    float inv = 1.0f / fmaxf(cnt[g], 1.0f);
    float acc = bc[c];
    for (int j = 0; j < HIDDEN; ++j)
        acc += pool[g * HIDDEN + j] * inv * Wc[j * N_CLASSES + c];
    out[t] = acc;
}

extern "C" void kernel_launch(void* const* d_in, const int* in_sizes, int n_in,
                              void* d_out, int out_size, void* d_ws, size_t ws_size,
                              hipStream_t stream) {
    const int*   src       = (const int*)d_in[0];
    const int*   dst       = (const int*)d_in[1];
    const int*   graph_ids = (const int*)d_in[2];
    const float* W1        = (const float*)d_in[3];
    const float* b1        = (const float*)d_in[4];
    const float* W2        = (const float*)d_in[5];
    const float* b2        = (const float*)d_in[6];
    const float* Wc        = (const float*)d_in[7];
    const float* bc        = (const float*)d_in[8];
    float* out = (float*)d_out;

    char* ws = (char*)d_ws;
    size_t off = 0;
    auto alloc = [&](size_t elems) { void* p = ws + off; off += elems * 4; return p; };

    // --- zeroed region (single ~82KB memset) ---
    uint*  bcur1 = (uint*) alloc(NBIN);                     // 8 KB
    uint*  bcur2 = (uint*) alloc(NBIN);                     // 8 KB
    float* pool  = (float*)alloc(N_GRAPHS * HIDDEN);        // 64 KB
    float* cnt   = (float*)alloc(N_GRAPHS);
    size_t zero_bytes = off;
    // --- non-zeroed ---
    float4* info = (float4*)alloc((size_t)NPAD * 4);        // 1.6 MB (16B-aligned)
    uint*   tmp1 = (uint*)  alloc((size_t)NBUCK * CAP);     // 12.8 MB
    uchar*  tmp2 = (uchar*) alloc((size_t)NBUCK * CAP / 4); // 3.2 MB
    float*  nsA  = (float*) alloc(NPAD);
    float*  hs0  = (float*) alloc(NPAD);
    float*  ndv  = (float*) alloc(NPAD);
    float*  U    = (float*) alloc(129 * HIDDEN);
    float*  V    = (float*) alloc(129 * HIDDEN);

    hipMemsetAsync(d_ws, 0, zero_bytes, stream);

    int pblocks = (N_EDGES + PCH - 1) / PCH;    // 391
    k_part <<<pblocks, PTH, 0, stream>>>(src, dst, bcur1, bcur2, tmp1, tmp2, N_EDGES);
    k_cnt  <<<NBUCK, 256, 0, stream>>>(bcur1, tmp1, bcur2, tmp2, nsA, hs0, ndv);
    k_info <<<NBUCK, 256, 0, stream>>>(bcur1, tmp1, hs0, nsA, ndv, W1, b1, W2, U, V, info);
    k_conv2<<<NBUCK, 256, 0, stream>>>(bcur1, tmp1, info, ndv, U, V, graph_ids, b2, pool, cnt);
    k_final<<<(N_GRAPHS * N_CLASSES + 255) / 256, 256, 0, stream>>>(pool, cnt, Wc, bc, out);
}